// Round 2
// baseline (515.063 us; speedup 1.0000x reference)
//
#include <hip/hip_runtime.h>
#include <hip/hip_bf16.h>

// AssignAttention: B=16, N=256, S=4096, C=512, H=8, hd=64
// out[b,n,h*64+c] = sum_s softmax_n(q.kT/8)[n,s]/max(rowsum,1) * key[b,s,h*64+c]
// d_out = [out, out_style] (identical copies), fp32.

typedef __attribute__((ext_vector_type(8))) short bf16x8;
typedef __attribute__((ext_vector_type(4))) float f32x4;
typedef unsigned int u32;

__device__ __forceinline__ unsigned short f2bf(float f) {
  union { __hip_bfloat16 h; unsigned short u; } cv;
  cv.h = __float2bfloat16(f);
  return cv.u;
}

// async global->LDS, 16B per lane. LDS dest = wave-uniform base + lane*16.
__device__ __forceinline__ void async_copy16(const void* gptr, void* lptr) {
  __builtin_amdgcn_global_load_lds((const __attribute__((address_space(1))) u32*)gptr,
                                   (__attribute__((address_space(3))) u32*)lptr,
                                   16, 0, 0);
}

// ---------------------------------------------------------------- prep: Wt[n][k] = bf16(W[k][n])
__global__ __launch_bounds__(256) void prep_w(const float* __restrict__ Wq,
                                              const float* __restrict__ Wk,
                                              unsigned short* __restrict__ WtQ,
                                              unsigned short* __restrict__ WtK) {
  int idx = blockIdx.x * 256 + threadIdx.x;   // 0 .. 262143
  int n = idx >> 9, k = idx & 511;
  WtQ[idx] = f2bf(Wq[k * 512 + n]);
  WtK[idx] = f2bf(Wk[k * 512 + n]);
}

// ---------------------------------------------------------------- GEMM: Y[m][n] = bf16( X[m][:] @ Wt[n][:] )
// X fp32 [M x 512] row-major, Wt bf16 [512 n x 512 k] (pre-transposed), Y bf16 [M x 512]
// m97-style: global_load_lds staging (A kept fp32 in LDS, cvt at fragment read).
// grid: (n-blocks = 4, m-blocks = M/128); 256 threads, 4 waves, 128x128 tile.
__global__ __launch_bounds__(256, 3) void gemm_xw(const float* __restrict__ X,
                                                  const unsigned short* __restrict__ Wt,
                                                  __hip_bfloat16* __restrict__ Y) {
  __shared__ float As[128 * 64];            // 32 KB, row-major stride 64 (no pad: DMA layout)
  __shared__ unsigned short Bs[128 * 64];   // 16 KB, row-major stride 64
  const int t = threadIdx.x;
  const int wave = t >> 6, lane = t & 63, l15 = lane & 15, quad = lane >> 4;
  const int n0 = blockIdx.x * 128, m0 = blockIdx.y * 128;
  const int wm = (wave >> 1) * 64, wn = (wave & 1) * 64;

  // per-lane source coordinates for the DMA issues
  const int arow = lane >> 4, acol = (lane & 15) << 2;   // A: 4 rows x 64 fp32 per issue
  const int brow = lane >> 3, bcol = (lane & 7) << 3;    // B: 8 rows x 64 bf16 per issue

  f32x4 acc[4][4];
#pragma unroll
  for (int i = 0; i < 4; ++i)
#pragma unroll
    for (int j = 0; j < 4; ++j) { f32x4 z = {0.f, 0.f, 0.f, 0.f}; acc[i][j] = z; }

  for (int k0 = 0; k0 < 512; k0 += 64) {
    __syncthreads();   // previous iteration's readers done before overwrite
    {
      const float* aBase = X + (size_t)m0 * 512 + k0;
#pragma unroll
      for (int o = 0; o < 8; ++o) {
        int rg = wave * 8 + o;               // row-group: rows rg*4 .. rg*4+3
        async_copy16(aBase + (size_t)(rg * 4 + arow) * 512 + acol, &As[rg * 256]);
      }
      const unsigned short* bBase = Wt + (size_t)n0 * 512 + k0;
#pragma unroll
      for (int o = 0; o < 4; ++o) {
        int rg = wave * 4 + o;               // row-group: rows rg*8 .. rg*8+7
        async_copy16(bBase + (size_t)(rg * 8 + brow) * 512 + bcol, &Bs[rg * 512]);
      }
    }
    __syncthreads();   // waits vmcnt(0): DMA complete

#pragma unroll
    for (int x = 0; x < 2; ++x) {
      bf16x8 a[4], bfr[4];
#pragma unroll
      for (int i = 0; i < 4; ++i) {
        const float* p = &As[(wm + 16 * i + l15) * 64 + x * 32 + quad * 8];
        float4 f0 = *reinterpret_cast<const float4*>(p);
        float4 f1 = *reinterpret_cast<const float4*>(p + 4);
        union { bf16x8 v; unsigned short s[8]; } u;
        u.s[0] = f2bf(f0.x); u.s[1] = f2bf(f0.y); u.s[2] = f2bf(f0.z); u.s[3] = f2bf(f0.w);
        u.s[4] = f2bf(f1.x); u.s[5] = f2bf(f1.y); u.s[6] = f2bf(f1.z); u.s[7] = f2bf(f1.w);
        a[i] = u.v;
      }
#pragma unroll
      for (int j = 0; j < 4; ++j)
        bfr[j] = *reinterpret_cast<const bf16x8*>(&Bs[(wn + 16 * j + l15) * 64 + x * 32 + quad * 8]);
#pragma unroll
      for (int i = 0; i < 4; ++i)
#pragma unroll
        for (int j = 0; j < 4; ++j)
          acc[i][j] = __builtin_amdgcn_mfma_f32_16x16x32_bf16(a[i], bfr[j], acc[i][j], 0, 0, 0);
    }
  }
  // epilogue: C/D layout col=lane&15, row=quad*4+reg
#pragma unroll
  for (int i = 0; i < 4; ++i)
#pragma unroll
    for (int j = 0; j < 4; ++j)
#pragma unroll
      for (int r = 0; r < 4; ++r) {
        int m = m0 + wm + 16 * i + 4 * quad + r;
        int n = n0 + wn + 16 * j + l15;
        Y[(size_t)m * 512 + n] = __float2bfloat16(acc[i][j][r]);
      }
}

// ---------------------------------------------------------------- fused attention
// grid 256: blk = bh*2 + chunk; per WG: q[256x64] (regs), loop 32 s-tiles of 64.
__global__ __launch_bounds__(256, 1) void attn_kernel(const __hip_bfloat16* __restrict__ qg,
                                                      const __hip_bfloat16* __restrict__ kg,
                                                      const float* __restrict__ keyg,
                                                      float* __restrict__ accg,
                                                      float* __restrict__ rsg) {
  __shared__ unsigned short ks[64][72];   // k_tile[s][c]
  __shared__ unsigned short vs[64][68];   // v_tile transposed [c][s], stride 68 -> 8B aligned rows
  __shared__ unsigned short ps[256][72];  // attn tile [n][s] (per-wave 64-row region)
  __shared__ float red[4][64];            // cross-wave column-sum partials

  const int t = threadIdx.x;
  const int wave = t >> 6, lane = t & 63, l15 = lane & 15, quad = lane >> 4;
  const int blk = blockIdx.x, chunk = blk & 1, bh = blk >> 1, b = bh >> 3, h = bh & 7;

  // q fragments in registers: rows [64*wave, +64), A-layout A[m=l15][k=quad*8+j]
  bf16x8 qf[4][2];
#pragma unroll
  for (int i = 0; i < 4; ++i)
#pragma unroll
    for (int x = 0; x < 2; ++x) {
      const unsigned short* p = (const unsigned short*)qg +
          (size_t)(b * 256 + wave * 64 + 16 * i + l15) * 512 + h * 64 + x * 32 + quad * 8;
      qf[i][x] = *reinterpret_cast<const bf16x8*>(p);
    }

  f32x4 oacc[4][4];
  float rs_[4][4];
#pragma unroll
  for (int i = 0; i < 4; ++i)
#pragma unroll
    for (int j = 0; j < 4; ++j) { f32x4 z = {0.f, 0.f, 0.f, 0.f}; oacc[i][j] = z; rs_[i][j] = 0.f; }

  const int s0base = chunk * 2048;
  for (int it = 0; it < 32; ++it) {
    const int s0 = s0base + it * 64;
    __syncthreads();  // protect ks/vs/red from previous iteration readers
    // stage k tile (bf16, rows of ks)
    {
      const unsigned short* kbase = (const unsigned short*)kg + ((size_t)(b * 4096 + s0)) * 512 + h * 64;
#pragma unroll
      for (int i = 0; i < 4; ++i) {
        int lin = i * 256 + t, row = lin >> 4, c4 = (lin & 15) << 2;
        *reinterpret_cast<short4*>(&ks[row][c4]) =
            *reinterpret_cast<const short4*>(kbase + (size_t)row * 512 + c4);
      }
      // stage v tile transposed, fp32 -> bf16
      const float* vbase = keyg + ((size_t)(b * 4096 + s0)) * 512 + h * 64;
#pragma unroll
      for (int i = 0; i < 4; ++i) {
        int lin = i * 256 + t, row = lin >> 4, c4 = (lin & 15) << 2;
        float4 v = *reinterpret_cast<const float4*>(vbase + (size_t)row * 512 + c4);
        vs[c4 + 0][row] = f2bf(v.x);
        vs[c4 + 1][row] = f2bf(v.y);
        vs[c4 + 2][row] = f2bf(v.z);
        vs[c4 + 3][row] = f2bf(v.w);
      }
    }
    __syncthreads();

    // L = q @ k_tile^T  (D rows = n-local, cols = s-local)
    f32x4 L[4][4];
#pragma unroll
    for (int i = 0; i < 4; ++i)
#pragma unroll
      for (int j = 0; j < 4; ++j) { f32x4 z = {0.f, 0.f, 0.f, 0.f}; L[i][j] = z; }
#pragma unroll
    for (int x = 0; x < 2; ++x) {
      bf16x8 bfr[4];
#pragma unroll
      for (int j = 0; j < 4; ++j)
        bfr[j] = *reinterpret_cast<const bf16x8*>(&ks[16 * j + l15][x * 32 + quad * 8]);
#pragma unroll
      for (int i = 0; i < 4; ++i)
#pragma unroll
        for (int j = 0; j < 4; ++j)
          L[i][j] = __builtin_amdgcn_mfma_f32_16x16x32_bf16(qf[i][x], bfr[j], L[i][j], 0, 0, 0);
    }

    // exp(l/8); column (n) sums: per-lane over i,r, then quads, then waves via LDS
    float csum[4] = {0.f, 0.f, 0.f, 0.f};
#pragma unroll
    for (int i = 0; i < 4; ++i)
#pragma unroll
      for (int j = 0; j < 4; ++j)
#pragma unroll
        for (int r = 0; r < 4; ++r) {
          float e = __expf(L[i][j][r] * 0.125f);
          L[i][j][r] = e;
          csum[j] += e;
        }
#pragma unroll
    for (int j = 0; j < 4; ++j) {
      float v = csum[j];
      v += __shfl_xor(v, 16);
      v += __shfl_xor(v, 32);
      csum[j] = v;
    }
    if (quad == 0) {
#pragma unroll
      for (int j = 0; j < 4; ++j) red[wave][16 * j + l15] = csum[j];
    }
    __syncthreads();
    float rcol[4];
#pragma unroll
    for (int j = 0; j < 4; ++j) {
      int s = 16 * j + l15;
      rcol[j] = 1.0f / (red[0][s] + red[1][s] + red[2][s] + red[3][s]);
    }

    // normalize -> attn; accumulate rowsum; write P tile (bf16) for A-operand reload
#pragma unroll
    for (int i = 0; i < 4; ++i)
#pragma unroll
      for (int r = 0; r < 4; ++r) {
        float rowpart = 0.f;
        int nloc = 16 * i + 4 * quad + r;
#pragma unroll
        for (int j = 0; j < 4; ++j) {
          float a = L[i][j][r] * rcol[j];
          rowpart += a;
          ps[wave * 64 + nloc][16 * j + l15] = f2bf(a);
        }
        rowpart += __shfl_xor(rowpart, 1);
        rowpart += __shfl_xor(rowpart, 2);
        rowpart += __shfl_xor(rowpart, 4);
        rowpart += __shfl_xor(rowpart, 8);
        rs_[i][r] += rowpart;
      }

    // O += P @ V   (B-operand from transposed vs)
#pragma unroll
    for (int x = 0; x < 2; ++x) {
      bf16x8 ap[4], bv[4];
#pragma unroll
      for (int i = 0; i < 4; ++i)
        ap[i] = *reinterpret_cast<const bf16x8*>(&ps[wave * 64 + 16 * i + l15][x * 32 + quad * 8]);
#pragma unroll
      for (int j = 0; j < 4; ++j) {
        const int* vp = reinterpret_cast<const int*>(&vs[16 * j + l15][x * 32 + quad * 8]);
        union { bf16x8 f; int w[4]; } u;
        u.w[0] = vp[0]; u.w[1] = vp[1]; u.w[2] = vp[2]; u.w[3] = vp[3];
        bv[j] = u.f;
      }
#pragma unroll
      for (int i = 0; i < 4; ++i)
#pragma unroll
        for (int j = 0; j < 4; ++j)
          oacc[i][j] = __builtin_amdgcn_mfma_f32_16x16x32_bf16(ap[i], bv[j], oacc[i][j], 0, 0, 0);
    }
  }

  // flush per-chunk partials (disjoint regions, no atomics)
  float* rsp = rsg + chunk * 32768 + bh * 256;
  if (l15 == 0) {
#pragma unroll
    for (int i = 0; i < 4; ++i)
#pragma unroll
      for (int r = 0; r < 4; ++r)
        rsp[wave * 64 + 16 * i + 4 * quad + r] = rs_[i][r];
  }
  float* ap_ = accg + (size_t)chunk * 2097152 + (size_t)bh * 16384;
#pragma unroll
  for (int i = 0; i < 4; ++i)
#pragma unroll
    for (int j = 0; j < 4; ++j)
#pragma unroll
      for (int r = 0; r < 4; ++r)
        ap_[(wave * 64 + 16 * i + 4 * quad + r) * 64 + 16 * j + l15] = oacc[i][j][r];
}

// ---------------------------------------------------------------- finalize: divide + write both outputs
__global__ __launch_bounds__(256) void finalize(const float* __restrict__ acc,
                                                const float* __restrict__ rs,
                                                float* __restrict__ out) {
  int idx = blockIdx.x * 256 + threadIdx.x;   // 0 .. 2097151
  int c = idx & 63, n = (idx >> 6) & 255, bh = idx >> 14;
  float v = acc[idx] + acc[idx + 2097152];
  float r = rs[bh * 256 + n] + rs[32768 + bh * 256 + n];
  float o = v / fmaxf(r, 1.0f);
  int b = bh >> 3, h = bh & 7;
  size_t oi = ((size_t)(b * 256 + n)) * 512 + h * 64 + c;
  out[oi] = o;
  out[oi + 2097152] = o;
}

extern "C" void kernel_launch(void* const* d_in, const int* in_sizes, int n_in,
                              void* d_out, int out_size, void* d_ws, size_t ws_size,
                              hipStream_t stream) {
  const float* query = (const float*)d_in[0];   // [16,256,512]
  const float* key   = (const float*)d_in[1];   // [16,4096,512]
  const float* Wq    = (const float*)d_in[2];   // [512,512]
  const float* Wk    = (const float*)d_in[3];   // [512,512]
  float* out = (float*)d_out;
  char* ws = (char*)d_ws;

  // ws layout (bytes):
  unsigned short* WtQ = (unsigned short*)(ws);                 // 512*512*2   = 524288
  unsigned short* WtK = (unsigned short*)(ws + 524288);        // 524288
  __hip_bfloat16* qbf = (__hip_bfloat16*)(ws + 1048576);       // 4096*512*2  = 4194304
  __hip_bfloat16* kbf = (__hip_bfloat16*)(ws + 5242880);       // 65536*512*2 = 67108864
  float* accw = (float*)(ws + 72351744);                       // 2*128*256*64*4 = 16777216
  float* rsw  = (float*)(ws + 89128960);                       // 2*128*256*4    = 262144
  // total: 89,391,104 bytes

  prep_w<<<1024, 256, 0, stream>>>(Wq, Wk, WtQ, WtK);
  gemm_xw<<<dim3(4, 32), 256, 0, stream>>>(query, WtQ, qbf);    // q = query @ Wq
  gemm_xw<<<dim3(4, 512), 256, 0, stream>>>(key, WtK, kbf);     // k = key @ Wk
  attn_kernel<<<256, 256, 0, stream>>>(qbf, kbf, key, accw, rsw);
  finalize<<<8192, 256, 0, stream>>>(accw, rsw, out);
}

// Round 3
// 388.226 us; speedup vs baseline: 1.3267x; 1.3267x over previous
//
#include <hip/hip_runtime.h>
#include <hip/hip_bf16.h>

// AssignAttention: B=16, N=256, S=4096, C=512, H=8, hd=64
// out[b,n,h*64+c] = sum_s softmax_n(q.kT/8)[n,s]/max(rowsum,1) * key[b,s,h*64+c]
// d_out = [out, out_style] (identical copies), fp32.

typedef __attribute__((ext_vector_type(8))) short bf16x8;
typedef __attribute__((ext_vector_type(4))) float f32x4;
typedef unsigned int u32;

__device__ __forceinline__ unsigned short f2bf(float f) {
  union { __hip_bfloat16 h; unsigned short u; } cv;
  cv.h = __float2bfloat16(f);
  return cv.u;
}

// async global->LDS, 16B per lane. LDS dest = wave-uniform base + lane*16.
__device__ __forceinline__ void async_copy16(const void* gptr, void* lptr) {
  __builtin_amdgcn_global_load_lds((const __attribute__((address_space(1))) u32*)gptr,
                                   (__attribute__((address_space(3))) u32*)lptr,
                                   16, 0, 0);
}

// ---------------------------------------------------------------- prep: Wt[n][k] = bf16(W[k][n])
// LDS tile transpose, coalesced read+write. grid: 128 blocks (64 tiles x 2 mats).
__global__ __launch_bounds__(256) void prep_w(const float* __restrict__ Wq,
                                              const float* __restrict__ Wk,
                                              unsigned short* __restrict__ WtQ,
                                              unsigned short* __restrict__ WtK) {
  __shared__ float tile[64][65];
  const int blk = blockIdx.x;
  const float* W = (blk & 1) ? Wk : Wq;
  unsigned short* Wt = (blk & 1) ? WtK : WtQ;
  const int tb = blk >> 1;                     // 0..63
  const int k0 = (tb >> 3) * 64, n0 = (tb & 7) * 64;
  const int t = threadIdx.x;
  const int row = t >> 4, col4 = (t & 15) * 4;
#pragma unroll
  for (int i = 0; i < 4; ++i) {
    int r = i * 16 + row;
    float4 v = *reinterpret_cast<const float4*>(&W[(size_t)(k0 + r) * 512 + n0 + col4]);
    tile[r][col4 + 0] = v.x; tile[r][col4 + 1] = v.y;
    tile[r][col4 + 2] = v.z; tile[r][col4 + 3] = v.w;
  }
  __syncthreads();
#pragma unroll
  for (int i = 0; i < 4; ++i) {
    int r = i * 16 + row;                      // n-local output row
    short4 s;
    s.x = (short)f2bf(tile[col4 + 0][r]);
    s.y = (short)f2bf(tile[col4 + 1][r]);
    s.z = (short)f2bf(tile[col4 + 2][r]);
    s.w = (short)f2bf(tile[col4 + 3][r]);
    *reinterpret_cast<short4*>(&Wt[(size_t)(n0 + r) * 512 + k0 + col4]) = s;
  }
}

// ---------------------------------------------------------------- GEMM: Y[m][n] = bf16( X[m][:] @ Wt[n][:] )
// X fp32 [M x 512] row-major, Wt bf16 [512 n x 512 k] (pre-transposed), Y bf16 [M x 512]
// DMA staging with XOR chunk swizzle to kill bank conflicts:
//   A (fp32, 16 chunks/row):  chunk (r,c) stored at phys r*16 + (c ^ (r&7))
//   B (bf16,  8 chunks/row):  chunk (r,c) stored at phys r*8  + (c ^ (r&7))
// grid: (n-blocks = 4, m-blocks = M/128); 256 threads, 4 waves, 128x128 tile.
__global__ __launch_bounds__(256, 3) void gemm_xw(const float* __restrict__ X,
                                                  const unsigned short* __restrict__ Wt,
                                                  __hip_bfloat16* __restrict__ Y) {
  __shared__ float As[128 * 64];            // 32 KB, swizzled chunk layout
  __shared__ unsigned short Bs[128 * 64];   // 16 KB, swizzled chunk layout
  const int t = threadIdx.x;
  const int wave = t >> 6, lane = t & 63, l15 = lane & 15, quad = lane >> 4;
  const int n0 = blockIdx.x * 128, m0 = blockIdx.y * 128;
  const int wm = (wave >> 1) * 64, wn = (wave & 1) * 64;

  // DMA source coords (per lane), with swizzled source-chunk selection.
  // A issue covers 4 rows x 16 chunks: lane p -> row_local p>>4, phys chunk p&15.
  const int a_rl = lane >> 4;                       // 0..3
  // B issue covers 8 rows x 8 chunks: lane p -> row_local p>>3, phys chunk p&7.
  const int b_rl = lane >> 3;                       // 0..7
  const int b_cs = (lane & 7) ^ b_rl;               // source chunk (row&7 == b_rl)

  f32x4 acc[4][4];
#pragma unroll
  for (int i = 0; i < 4; ++i)
#pragma unroll
    for (int j = 0; j < 4; ++j) { f32x4 z = {0.f, 0.f, 0.f, 0.f}; acc[i][j] = z; }

  for (int k0 = 0; k0 < 512; k0 += 64) {
    __syncthreads();   // previous iteration's readers done before overwrite
    {
      const float* aBase = X + (size_t)m0 * 512 + k0;
#pragma unroll
      for (int o = 0; o < 8; ++o) {
        int rg = wave * 8 + o;                      // rows rg*4 .. rg*4+3
        int r = rg * 4 + a_rl;
        int cs = (lane & 15) ^ (r & 7);             // source chunk
        async_copy16(aBase + (size_t)r * 512 + cs * 4, &As[rg * 256]);
      }
      const unsigned short* bBase = Wt + (size_t)n0 * 512 + k0;
#pragma unroll
      for (int o = 0; o < 4; ++o) {
        int rg = wave * 4 + o;                      // rows rg*8 .. rg*8+7
        int r = rg * 8 + b_rl;
        async_copy16(bBase + (size_t)r * 512 + b_cs * 8, &Bs[rg * 512]);
      }
    }
    __syncthreads();   // waits vmcnt(0): DMA complete

#pragma unroll
    for (int x = 0; x < 2; ++x) {
      bf16x8 a[4], bfr[4];
#pragma unroll
      for (int i = 0; i < 4; ++i) {
        int ra = wm + 16 * i + l15;
        int c0 = x * 8 + quad * 2;                  // fp32 chunk index (4 floats/chunk)
        float4 f0 = *reinterpret_cast<const float4*>(&As[(ra * 16 + (c0 ^ (ra & 7))) * 4]);
        float4 f1 = *reinterpret_cast<const float4*>(&As[(ra * 16 + ((c0 + 1) ^ (ra & 7))) * 4]);
        union { bf16x8 v; unsigned short s[8]; } u;
        u.s[0] = f2bf(f0.x); u.s[1] = f2bf(f0.y); u.s[2] = f2bf(f0.z); u.s[3] = f2bf(f0.w);
        u.s[4] = f2bf(f1.x); u.s[5] = f2bf(f1.y); u.s[6] = f2bf(f1.z); u.s[7] = f2bf(f1.w);
        a[i] = u.v;
      }
#pragma unroll
      for (int j = 0; j < 4; ++j) {
        int rb = wn + 16 * j + l15;
        int cb = x * 4 + quad;                      // bf16 chunk index (8 shorts/chunk)
        bfr[j] = *reinterpret_cast<const bf16x8*>(&Bs[(rb * 8 + (cb ^ (rb & 7))) * 8]);
      }
#pragma unroll
      for (int i = 0; i < 4; ++i)
#pragma unroll
        for (int j = 0; j < 4; ++j)
          acc[i][j] = __builtin_amdgcn_mfma_f32_16x16x32_bf16(a[i], bfr[j], acc[i][j], 0, 0, 0);
    }
  }
  // epilogue: C/D layout col=lane&15, row=quad*4+reg
#pragma unroll
  for (int i = 0; i < 4; ++i)
#pragma unroll
    for (int j = 0; j < 4; ++j)
#pragma unroll
      for (int r = 0; r < 4; ++r) {
        int m = m0 + wm + 16 * i + 4 * quad + r;
        int n = n0 + wn + 16 * j + l15;
        Y[(size_t)m * 512 + n] = __float2bfloat16(acc[i][j][r]);
      }
}

// ---------------------------------------------------------------- fused attention
// grid 256: blk = bh*2 + chunk; per WG: q[256x64] (regs), loop 32 s-tiles of 64.
__global__ __launch_bounds__(256, 1) void attn_kernel(const __hip_bfloat16* __restrict__ qg,
                                                      const __hip_bfloat16* __restrict__ kg,
                                                      const float* __restrict__ keyg,
                                                      float* __restrict__ accg,
                                                      float* __restrict__ rsg) {
  __shared__ unsigned short ks[64][72];   // k_tile[s][c]
  __shared__ unsigned short vs[64][68];   // v_tile transposed [c][s], stride 68 -> 8B aligned rows
  __shared__ unsigned short ps[256][72];  // attn tile [n][s] (per-wave 64-row region)
  __shared__ float red[4][64];            // cross-wave column-sum partials

  const int t = threadIdx.x;
  const int wave = t >> 6, lane = t & 63, l15 = lane & 15, quad = lane >> 4;
  const int blk = blockIdx.x, chunk = blk & 1, bh = blk >> 1, b = bh >> 3, h = bh & 7;

  // q fragments in registers: rows [64*wave, +64), A-layout A[m=l15][k=quad*8+j]
  bf16x8 qf[4][2];
#pragma unroll
  for (int i = 0; i < 4; ++i)
#pragma unroll
    for (int x = 0; x < 2; ++x) {
      const unsigned short* p = (const unsigned short*)qg +
          (size_t)(b * 256 + wave * 64 + 16 * i + l15) * 512 + h * 64 + x * 32 + quad * 8;
      qf[i][x] = *reinterpret_cast<const bf16x8*>(p);
    }

  f32x4 oacc[4][4];
  float rs_[4][4];
#pragma unroll
  for (int i = 0; i < 4; ++i)
#pragma unroll
    for (int j = 0; j < 4; ++j) { f32x4 z = {0.f, 0.f, 0.f, 0.f}; oacc[i][j] = z; rs_[i][j] = 0.f; }

  const int s0base = chunk * 2048;
  for (int it = 0; it < 32; ++it) {
    const int s0 = s0base + it * 64;
    __syncthreads();  // protect ks/vs/red from previous iteration readers
    // stage k tile (bf16, rows of ks)
    {
      const unsigned short* kbase = (const unsigned short*)kg + ((size_t)(b * 4096 + s0)) * 512 + h * 64;
#pragma unroll
      for (int i = 0; i < 4; ++i) {
        int lin = i * 256 + t, row = lin >> 4, c4 = (lin & 15) << 2;
        *reinterpret_cast<short4*>(&ks[row][c4]) =
            *reinterpret_cast<const short4*>(kbase + (size_t)row * 512 + c4);
      }
      // stage v tile transposed, fp32 -> bf16
      const float* vbase = keyg + ((size_t)(b * 4096 + s0)) * 512 + h * 64;
#pragma unroll
      for (int i = 0; i < 4; ++i) {
        int lin = i * 256 + t, row = lin >> 4, c4 = (lin & 15) << 2;
        float4 v = *reinterpret_cast<const float4*>(vbase + (size_t)row * 512 + c4);
        vs[c4 + 0][row] = f2bf(v.x);
        vs[c4 + 1][row] = f2bf(v.y);
        vs[c4 + 2][row] = f2bf(v.z);
        vs[c4 + 3][row] = f2bf(v.w);
      }
    }
    __syncthreads();

    // L = q @ k_tile^T  (D rows = n-local, cols = s-local)
    f32x4 L[4][4];
#pragma unroll
    for (int i = 0; i < 4; ++i)
#pragma unroll
      for (int j = 0; j < 4; ++j) { f32x4 z = {0.f, 0.f, 0.f, 0.f}; L[i][j] = z; }
#pragma unroll
    for (int x = 0; x < 2; ++x) {
      bf16x8 bfr[4];
#pragma unroll
      for (int j = 0; j < 4; ++j)
        bfr[j] = *reinterpret_cast<const bf16x8*>(&ks[16 * j + l15][x * 32 + quad * 8]);
#pragma unroll
      for (int i = 0; i < 4; ++i)
#pragma unroll
        for (int j = 0; j < 4; ++j)
          L[i][j] = __builtin_amdgcn_mfma_f32_16x16x32_bf16(qf[i][x], bfr[j], L[i][j], 0, 0, 0);
    }

    // exp(l/8); column (n) sums: per-lane over i,r, then quads, then waves via LDS
    float csum[4] = {0.f, 0.f, 0.f, 0.f};
#pragma unroll
    for (int i = 0; i < 4; ++i)
#pragma unroll
      for (int j = 0; j < 4; ++j)
#pragma unroll
        for (int r = 0; r < 4; ++r) {
          float e = __expf(L[i][j][r] * 0.125f);
          L[i][j][r] = e;
          csum[j] += e;
        }
#pragma unroll
    for (int j = 0; j < 4; ++j) {
      float v = csum[j];
      v += __shfl_xor(v, 16);
      v += __shfl_xor(v, 32);
      csum[j] = v;
    }
    if (quad == 0) {
#pragma unroll
      for (int j = 0; j < 4; ++j) red[wave][16 * j + l15] = csum[j];
    }
    __syncthreads();
    float rcol[4];
#pragma unroll
    for (int j = 0; j < 4; ++j) {
      int s = 16 * j + l15;
      rcol[j] = 1.0f / (red[0][s] + red[1][s] + red[2][s] + red[3][s]);
    }

    // normalize -> attn; accumulate rowsum; write P tile (bf16) for A-operand reload
#pragma unroll
    for (int i = 0; i < 4; ++i)
#pragma unroll
      for (int r = 0; r < 4; ++r) {
        float rowpart = 0.f;
        int nloc = 16 * i + 4 * quad + r;
#pragma unroll
        for (int j = 0; j < 4; ++j) {
          float a = L[i][j][r] * rcol[j];
          rowpart += a;
          ps[wave * 64 + nloc][16 * j + l15] = f2bf(a);
        }
        rowpart += __shfl_xor(rowpart, 1);
        rowpart += __shfl_xor(rowpart, 2);
        rowpart += __shfl_xor(rowpart, 4);
        rowpart += __shfl_xor(rowpart, 8);
        rs_[i][r] += rowpart;
      }

    // O += P @ V   (B-operand from transposed vs)
#pragma unroll
    for (int x = 0; x < 2; ++x) {
      bf16x8 ap[4], bv[4];
#pragma unroll
      for (int i = 0; i < 4; ++i)
        ap[i] = *reinterpret_cast<const bf16x8*>(&ps[wave * 64 + 16 * i + l15][x * 32 + quad * 8]);
#pragma unroll
      for (int j = 0; j < 4; ++j) {
        const int* vp = reinterpret_cast<const int*>(&vs[16 * j + l15][x * 32 + quad * 8]);
        union { bf16x8 f; int w[4]; } u;
        u.w[0] = vp[0]; u.w[1] = vp[1]; u.w[2] = vp[2]; u.w[3] = vp[3];
        bv[j] = u.f;
      }
#pragma unroll
      for (int i = 0; i < 4; ++i)
#pragma unroll
        for (int j = 0; j < 4; ++j)
          oacc[i][j] = __builtin_amdgcn_mfma_f32_16x16x32_bf16(ap[i], bv[j], oacc[i][j], 0, 0, 0);
    }
  }

  // flush per-chunk partials (disjoint regions, no atomics)
  float* rsp = rsg + chunk * 32768 + bh * 256;
  if (l15 == 0) {
#pragma unroll
    for (int i = 0; i < 4; ++i)
#pragma unroll
      for (int r = 0; r < 4; ++r)
        rsp[wave * 64 + 16 * i + 4 * quad + r] = rs_[i][r];
  }
  float* ap_ = accg + (size_t)chunk * 2097152 + (size_t)bh * 16384;
#pragma unroll
  for (int i = 0; i < 4; ++i)
#pragma unroll
    for (int j = 0; j < 4; ++j)
#pragma unroll
      for (int r = 0; r < 4; ++r)
        ap_[(wave * 64 + 16 * i + 4 * quad + r) * 64 + 16 * j + l15] = oacc[i][j][r];
}

// ---------------------------------------------------------------- finalize: divide + write both outputs
__global__ __launch_bounds__(256) void finalize(const float* __restrict__ acc,
                                                const float* __restrict__ rs,
                                                float* __restrict__ out) {
  int idx = blockIdx.x * 256 + threadIdx.x;   // 0 .. 2097151
  int c = idx & 63, n = (idx >> 6) & 255, bh = idx >> 14;
  float v = acc[idx] + acc[idx + 2097152];
  float r = rs[bh * 256 + n] + rs[32768 + bh * 256 + n];
  float o = v / fmaxf(r, 1.0f);
  int b = bh >> 3, h = bh & 7;
  size_t oi = ((size_t)(b * 256 + n)) * 512 + h * 64 + c;
  out[oi] = o;
  out[oi + 2097152] = o;
}

extern "C" void kernel_launch(void* const* d_in, const int* in_sizes, int n_in,
                              void* d_out, int out_size, void* d_ws, size_t ws_size,
                              hipStream_t stream) {
  const float* query = (const float*)d_in[0];   // [16,256,512]
  const float* key   = (const float*)d_in[1];   // [16,4096,512]
  const float* Wq    = (const float*)d_in[2];   // [512,512]
  const float* Wk    = (const float*)d_in[3];   // [512,512]
  float* out = (float*)d_out;
  char* ws = (char*)d_ws;

  // ws layout (bytes):
  unsigned short* WtQ = (unsigned short*)(ws);                 // 512*512*2   = 524288
  unsigned short* WtK = (unsigned short*)(ws + 524288);        // 524288
  __hip_bfloat16* qbf = (__hip_bfloat16*)(ws + 1048576);       // 4096*512*2  = 4194304
  __hip_bfloat16* kbf = (__hip_bfloat16*)(ws + 5242880);       // 65536*512*2 = 67108864
  float* accw = (float*)(ws + 72351744);                       // 2*128*256*64*4 = 16777216
  float* rsw  = (float*)(ws + 89128960);                       // 2*128*256*4    = 262144
  // total: 89,391,104 bytes

  prep_w<<<128, 256, 0, stream>>>(Wq, Wk, WtQ, WtK);
  gemm_xw<<<dim3(4, 32), 256, 0, stream>>>(query, WtQ, qbf);    // q = query @ Wq
  gemm_xw<<<dim3(4, 512), 256, 0, stream>>>(key, WtK, kbf);     // k = key @ Wk
  attn_kernel<<<256, 256, 0, stream>>>(qbf, kbf, key, accw, rsw);
  finalize<<<8192, 256, 0, stream>>>(accw, rsw, out);
}

// Round 4
// 354.283 us; speedup vs baseline: 1.4538x; 1.0958x over previous
//
#include <hip/hip_runtime.h>
#include <hip/hip_bf16.h>

// AssignAttention: B=16, N=256, S=4096, C=512, H=8, hd=64
// out[b,n,h*64+c] = sum_s softmax_n(q.kT/8)[n,s]/max(rowsum,1) * key[b,s,h*64+c]
// d_out = [out, out_style] (identical copies), fp32.

typedef __attribute__((ext_vector_type(8))) short bf16x8;
typedef __attribute__((ext_vector_type(4))) float f32x4;
typedef unsigned int u32;

__device__ __forceinline__ unsigned short f2bf(float f) {
  union { __hip_bfloat16 h; unsigned short u; } cv;
  cv.h = __float2bfloat16(f);
  return cv.u;
}

// async global->LDS, 16B per lane. LDS dest = wave-uniform base + lane*16.
__device__ __forceinline__ void async_copy16(const void* gptr, void* lptr) {
  __builtin_amdgcn_global_load_lds((const __attribute__((address_space(1))) u32*)gptr,
                                   (__attribute__((address_space(3))) u32*)lptr,
                                   16, 0, 0);
}

// ---------------------------------------------------------------- prep: Wt[n][k] = bf16(W[k][n])
// LDS tile transpose, coalesced read+write. grid: 128 blocks (64 tiles x 2 mats).
__global__ __launch_bounds__(256) void prep_w(const float* __restrict__ Wq,
                                              const float* __restrict__ Wk,
                                              unsigned short* __restrict__ WtQ,
                                              unsigned short* __restrict__ WtK) {
  __shared__ float tile[64][65];
  const int blk = blockIdx.x;
  const float* W = (blk & 1) ? Wk : Wq;
  unsigned short* Wt = (blk & 1) ? WtK : WtQ;
  const int tb = blk >> 1;                     // 0..63
  const int k0 = (tb >> 3) * 64, n0 = (tb & 7) * 64;
  const int t = threadIdx.x;
  const int row = t >> 4, col4 = (t & 15) * 4;
#pragma unroll
  for (int i = 0; i < 4; ++i) {
    int r = i * 16 + row;
    float4 v = *reinterpret_cast<const float4*>(&W[(size_t)(k0 + r) * 512 + n0 + col4]);
    tile[r][col4 + 0] = v.x; tile[r][col4 + 1] = v.y;
    tile[r][col4 + 2] = v.z; tile[r][col4 + 3] = v.w;
  }
  __syncthreads();
#pragma unroll
  for (int i = 0; i < 4; ++i) {
    int r = i * 16 + row;                      // n-local output row
    short4 s;
    s.x = (short)f2bf(tile[col4 + 0][r]);
    s.y = (short)f2bf(tile[col4 + 1][r]);
    s.z = (short)f2bf(tile[col4 + 2][r]);
    s.w = (short)f2bf(tile[col4 + 3][r]);
    *reinterpret_cast<short4*>(&Wt[(size_t)(n0 + r) * 512 + k0 + col4]) = s;
  }
}

// ---------------------------------------------------------------- GEMM: Y[m][n] = bf16( X[m][:] @ Wt[n][:] )
// X fp32 [M x 512] row-major, Wt bf16 [512 n x 512 k] (pre-transposed), Y bf16 [M x 512]
// DMA staging with XOR chunk swizzle to kill bank conflicts:
//   A (fp32, 16 chunks/row):  chunk (r,c) stored at phys r*16 + (c ^ (r&7))
//   B (bf16,  8 chunks/row):  chunk (r,c) stored at phys r*8  + (c ^ (r&7))
// grid: (n-blocks = 4, m-blocks = M/128); 256 threads, 4 waves, 128x128 tile.
__global__ __launch_bounds__(256, 3) void gemm_xw(const float* __restrict__ X,
                                                  const unsigned short* __restrict__ Wt,
                                                  __hip_bfloat16* __restrict__ Y) {
  __shared__ float As[128 * 64];            // 32 KB, swizzled chunk layout
  __shared__ unsigned short Bs[128 * 64];   // 16 KB, swizzled chunk layout
  const int t = threadIdx.x;
  const int wave = t >> 6, lane = t & 63, l15 = lane & 15, quad = lane >> 4;
  const int n0 = blockIdx.x * 128, m0 = blockIdx.y * 128;
  const int wm = (wave >> 1) * 64, wn = (wave & 1) * 64;

  const int a_rl = lane >> 4;                       // 0..3
  const int b_rl = lane >> 3;                       // 0..7
  const int b_cs = (lane & 7) ^ b_rl;               // source chunk (row&7 == b_rl)

  f32x4 acc[4][4];
#pragma unroll
  for (int i = 0; i < 4; ++i)
#pragma unroll
    for (int j = 0; j < 4; ++j) { f32x4 z = {0.f, 0.f, 0.f, 0.f}; acc[i][j] = z; }

  for (int k0 = 0; k0 < 512; k0 += 64) {
    __syncthreads();   // previous iteration's readers done before overwrite
    {
      const float* aBase = X + (size_t)m0 * 512 + k0;
#pragma unroll
      for (int o = 0; o < 8; ++o) {
        int rg = wave * 8 + o;                      // rows rg*4 .. rg*4+3
        int r = rg * 4 + a_rl;
        int cs = (lane & 15) ^ (r & 7);             // source chunk
        async_copy16(aBase + (size_t)r * 512 + cs * 4, &As[rg * 256]);
      }
      const unsigned short* bBase = Wt + (size_t)n0 * 512 + k0;
#pragma unroll
      for (int o = 0; o < 4; ++o) {
        int rg = wave * 4 + o;                      // rows rg*8 .. rg*8+7
        int r = rg * 8 + b_rl;
        async_copy16(bBase + (size_t)r * 512 + b_cs * 8, &Bs[rg * 512]);
      }
    }
    __syncthreads();   // waits vmcnt(0): DMA complete

#pragma unroll
    for (int x = 0; x < 2; ++x) {
      bf16x8 a[4], bfr[4];
#pragma unroll
      for (int i = 0; i < 4; ++i) {
        int ra = wm + 16 * i + l15;
        int c0 = x * 8 + quad * 2;                  // fp32 chunk index (4 floats/chunk)
        float4 f0 = *reinterpret_cast<const float4*>(&As[(ra * 16 + (c0 ^ (ra & 7))) * 4]);
        float4 f1 = *reinterpret_cast<const float4*>(&As[(ra * 16 + ((c0 + 1) ^ (ra & 7))) * 4]);
        union { bf16x8 v; unsigned short s[8]; } u;
        u.s[0] = f2bf(f0.x); u.s[1] = f2bf(f0.y); u.s[2] = f2bf(f0.z); u.s[3] = f2bf(f0.w);
        u.s[4] = f2bf(f1.x); u.s[5] = f2bf(f1.y); u.s[6] = f2bf(f1.z); u.s[7] = f2bf(f1.w);
        a[i] = u.v;
      }
#pragma unroll
      for (int j = 0; j < 4; ++j) {
        int rb = wn + 16 * j + l15;
        int cb = x * 4 + quad;                      // bf16 chunk index (8 shorts/chunk)
        bfr[j] = *reinterpret_cast<const bf16x8*>(&Bs[(rb * 8 + (cb ^ (rb & 7))) * 8]);
      }
#pragma unroll
      for (int i = 0; i < 4; ++i)
#pragma unroll
        for (int j = 0; j < 4; ++j)
          acc[i][j] = __builtin_amdgcn_mfma_f32_16x16x32_bf16(a[i], bfr[j], acc[i][j], 0, 0, 0);
    }
  }
  // epilogue: C/D layout col=lane&15, row=quad*4+reg
#pragma unroll
  for (int i = 0; i < 4; ++i)
#pragma unroll
    for (int j = 0; j < 4; ++j)
#pragma unroll
      for (int r = 0; r < 4; ++r) {
        int m = m0 + wm + 16 * i + 4 * quad + r;
        int n = n0 + wn + 16 * j + l15;
        Y[(size_t)m * 512 + n] = __float2bfloat16(acc[i][j][r]);
      }
}

// ---------------------------------------------------------------- fused attention
// grid 256 (blk = bh*2 + chunk), 512 threads (8 waves x 32 q-rows each),
// loop 32 s-tiles of 64. sigma(s)=4*(s&15)+(s>>4) permutes the PV contraction
// axis (applied to both P cols and V^T rows) so ps writes pack to b64.
__global__ __launch_bounds__(512, 2) void attn_kernel(const __hip_bfloat16* __restrict__ qg,
                                                      const __hip_bfloat16* __restrict__ kg,
                                                      const float* __restrict__ keyg,
                                                      float* __restrict__ accg,
                                                      float* __restrict__ rsg) {
  __shared__ unsigned short ks[64][72];   // k_tile[s][c]
  __shared__ unsigned short vs[64][66];   // v_tile transposed [c][sigma(s)]
  __shared__ unsigned short ps[256][72];  // attn tile [n][sigma(s)] (per-wave 32-row region)
  __shared__ float red[8][64];            // cross-wave column-sum partials

  const int t = threadIdx.x;
  const int wave = t >> 6, lane = t & 63, l15 = lane & 15, quad = lane >> 4;
  const int blk = blockIdx.x, chunk = blk & 1, bh = blk >> 1, b = bh >> 3, h = bh & 7;

  // q fragments in registers: rows [32*wave, +32), A-layout A[m=l15][k=quad*8+j]
  bf16x8 qf[2][2];
#pragma unroll
  for (int i = 0; i < 2; ++i)
#pragma unroll
    for (int x = 0; x < 2; ++x) {
      const unsigned short* p = (const unsigned short*)qg +
          (size_t)(b * 256 + wave * 32 + 16 * i + l15) * 512 + h * 64 + x * 32 + quad * 8;
      qf[i][x] = *reinterpret_cast<const bf16x8*>(p);
    }

  // ones B-fragment for the MFMA rowsum (bf16 1.0 splat)
  union { bf16x8 f; int w[4]; } ones_u;
  ones_u.w[0] = 0x3F803F80; ones_u.w[1] = 0x3F803F80;
  ones_u.w[2] = 0x3F803F80; ones_u.w[3] = 0x3F803F80;
  const bf16x8 ones = ones_u.f;

  f32x4 oacc[2][4], rsacc[2];
#pragma unroll
  for (int i = 0; i < 2; ++i) {
    f32x4 z = {0.f, 0.f, 0.f, 0.f};
    rsacc[i] = z;
#pragma unroll
    for (int j = 0; j < 4; ++j) oacc[i][j] = z;
  }

  const int s0base = chunk * 2048;
  for (int it = 0; it < 32; ++it) {
    const int s0 = s0base + it * 64;
    __syncthreads();  // protect ks/vs/red from previous iteration readers
    // stage k tile (bf16, rows of ks)
    {
      const unsigned short* kbase = (const unsigned short*)kg + ((size_t)(b * 4096 + s0)) * 512 + h * 64;
#pragma unroll
      for (int i = 0; i < 2; ++i) {
        int lin = i * 512 + t, row = lin >> 4, c4 = (lin & 15) << 2;
        *reinterpret_cast<short4*>(&ks[row][c4]) =
            *reinterpret_cast<const short4*>(kbase + (size_t)row * 512 + c4);
      }
      // stage v tile transposed + sigma-permuted, fp32 -> bf16
      const float* vbase = keyg + ((size_t)(b * 4096 + s0)) * 512 + h * 64;
#pragma unroll
      for (int i = 0; i < 2; ++i) {
        int lin = i * 512 + t, row = lin >> 4, c4 = (lin & 15) << 2;
        int sig = 4 * (row & 15) + (row >> 4);
        float4 v = *reinterpret_cast<const float4*>(vbase + (size_t)row * 512 + c4);
        vs[c4 + 0][sig] = f2bf(v.x);
        vs[c4 + 1][sig] = f2bf(v.y);
        vs[c4 + 2][sig] = f2bf(v.z);
        vs[c4 + 3][sig] = f2bf(v.w);
      }
    }
    __syncthreads();

    // L = q @ k_tile^T  (D rows = n-local, cols = s-local)
    f32x4 L[2][4];
#pragma unroll
    for (int i = 0; i < 2; ++i)
#pragma unroll
      for (int j = 0; j < 4; ++j) { f32x4 z = {0.f, 0.f, 0.f, 0.f}; L[i][j] = z; }
#pragma unroll
    for (int x = 0; x < 2; ++x) {
      bf16x8 bfr[4];
#pragma unroll
      for (int j = 0; j < 4; ++j)
        bfr[j] = *reinterpret_cast<const bf16x8*>(&ks[16 * j + l15][x * 32 + quad * 8]);
#pragma unroll
      for (int i = 0; i < 2; ++i)
#pragma unroll
        for (int j = 0; j < 4; ++j)
          L[i][j] = __builtin_amdgcn_mfma_f32_16x16x32_bf16(qf[i][x], bfr[j], L[i][j], 0, 0, 0);
    }

    // exp(l/8); column (n) sums: per-lane over i,r, then quads, then 8 waves via LDS
    float csum[4] = {0.f, 0.f, 0.f, 0.f};
#pragma unroll
    for (int i = 0; i < 2; ++i)
#pragma unroll
      for (int j = 0; j < 4; ++j)
#pragma unroll
        for (int r = 0; r < 4; ++r) {
          float e = __expf(L[i][j][r] * 0.125f);
          L[i][j][r] = e;
          csum[j] += e;
        }
#pragma unroll
    for (int j = 0; j < 4; ++j) {
      float v = csum[j];
      v += __shfl_xor(v, 16);
      v += __shfl_xor(v, 32);
      csum[j] = v;
    }
    if (quad == 0) {
#pragma unroll
      for (int j = 0; j < 4; ++j) red[wave][16 * j + l15] = csum[j];
    }
    __syncthreads();
    float rcol[4];
#pragma unroll
    for (int j = 0; j < 4; ++j) {
      int s = 16 * j + l15;
      rcol[j] = 1.0f / (red[0][s] + red[1][s] + red[2][s] + red[3][s] +
                        red[4][s] + red[5][s] + red[6][s] + red[7][s]);
    }

    // normalize -> attn; write P tile packed b64 at sigma-columns 4*l15+j
#pragma unroll
    for (int i = 0; i < 2; ++i)
#pragma unroll
      for (int r = 0; r < 4; ++r) {
        int nloc = wave * 32 + 16 * i + 4 * quad + r;
        short4 s4;
        s4.x = (short)f2bf(L[i][0][r] * rcol[0]);
        s4.y = (short)f2bf(L[i][1][r] * rcol[1]);
        s4.z = (short)f2bf(L[i][2][r] * rcol[2]);
        s4.w = (short)f2bf(L[i][3][r] * rcol[3]);
        *reinterpret_cast<short4*>(&ps[nloc][4 * l15]) = s4;
      }

    // O += P @ V ; rowsum += P @ ones  (all in sigma-space, permutation-invariant)
#pragma unroll
    for (int x = 0; x < 2; ++x) {
      bf16x8 ap[2], bv[4];
#pragma unroll
      for (int i = 0; i < 2; ++i)
        ap[i] = *reinterpret_cast<const bf16x8*>(&ps[wave * 32 + 16 * i + l15][x * 32 + quad * 8]);
#pragma unroll
      for (int j = 0; j < 4; ++j) {
        const int* vp = reinterpret_cast<const int*>(&vs[16 * j + l15][x * 32 + quad * 8]);
        union { bf16x8 f; int w[4]; } u;
        u.w[0] = vp[0]; u.w[1] = vp[1]; u.w[2] = vp[2]; u.w[3] = vp[3];
        bv[j] = u.f;
      }
#pragma unroll
      for (int i = 0; i < 2; ++i) {
#pragma unroll
        for (int j = 0; j < 4; ++j)
          oacc[i][j] = __builtin_amdgcn_mfma_f32_16x16x32_bf16(ap[i], bv[j], oacc[i][j], 0, 0, 0);
        rsacc[i] = __builtin_amdgcn_mfma_f32_16x16x32_bf16(ap[i], ones, rsacc[i], 0, 0, 0);
      }
    }
  }

  // flush per-chunk partials (disjoint regions, no atomics)
  float* rsp = rsg + chunk * 32768 + bh * 256;
  if (l15 == 0) {
#pragma unroll
    for (int i = 0; i < 2; ++i)
#pragma unroll
      for (int r = 0; r < 4; ++r)
        rsp[wave * 32 + 16 * i + 4 * quad + r] = rsacc[i][r];
  }
  float* ap_ = accg + (size_t)chunk * 2097152 + (size_t)bh * 16384;
#pragma unroll
  for (int i = 0; i < 2; ++i)
#pragma unroll
    for (int j = 0; j < 4; ++j)
#pragma unroll
      for (int r = 0; r < 4; ++r)
        ap_[(wave * 32 + 16 * i + 4 * quad + r) * 64 + 16 * j + l15] = oacc[i][j][r];
}

// ---------------------------------------------------------------- finalize: divide + write both outputs
__global__ __launch_bounds__(256) void finalize(const float* __restrict__ acc,
                                                const float* __restrict__ rs,
                                                float* __restrict__ out) {
  int idx = blockIdx.x * 256 + threadIdx.x;   // 0 .. 2097151
  int c = idx & 63, n = (idx >> 6) & 255, bh = idx >> 14;
  float v = acc[idx] + acc[idx + 2097152];
  float r = rs[bh * 256 + n] + rs[32768 + bh * 256 + n];
  float o = v / fmaxf(r, 1.0f);
  int b = bh >> 3, h = bh & 7;
  size_t oi = ((size_t)(b * 256 + n)) * 512 + h * 64 + c;
  out[oi] = o;
  out[oi + 2097152] = o;
}

extern "C" void kernel_launch(void* const* d_in, const int* in_sizes, int n_in,
                              void* d_out, int out_size, void* d_ws, size_t ws_size,
                              hipStream_t stream) {
  const float* query = (const float*)d_in[0];   // [16,256,512]
  const float* key   = (const float*)d_in[1];   // [16,4096,512]
  const float* Wq    = (const float*)d_in[2];   // [512,512]
  const float* Wk    = (const float*)d_in[3];   // [512,512]
  float* out = (float*)d_out;
  char* ws = (char*)d_ws;

  // ws layout (bytes):
  unsigned short* WtQ = (unsigned short*)(ws);                 // 512*512*2   = 524288
  unsigned short* WtK = (unsigned short*)(ws + 524288);        // 524288
  __hip_bfloat16* qbf = (__hip_bfloat16*)(ws + 1048576);       // 4096*512*2  = 4194304
  __hip_bfloat16* kbf = (__hip_bfloat16*)(ws + 5242880);       // 65536*512*2 = 67108864
  float* accw = (float*)(ws + 72351744);                       // 2*128*256*64*4 = 16777216
  float* rsw  = (float*)(ws + 89128960);                       // 2*128*256*4    = 262144
  // total: 89,391,104 bytes

  prep_w<<<128, 256, 0, stream>>>(Wq, Wk, WtQ, WtK);
  gemm_xw<<<dim3(4, 32), 256, 0, stream>>>(query, WtQ, qbf);    // q = query @ Wq
  gemm_xw<<<dim3(4, 512), 256, 0, stream>>>(key, WtK, kbf);     // k = key @ Wk
  attn_kernel<<<256, 512, 0, stream>>>(qbf, kbf, key, accw, rsw);
  finalize<<<8192, 256, 0, stream>>>(accw, rsw, out);
}